// Round 2
// baseline (325.334 us; speedup 1.0000x reference)
//
#include <hip/hip_runtime.h>
#include <stdint.h>

// S6Layer on MI355X. B=8, L=4096, DM=256, DI=384, DS=8, CHUNK=32.
// Stages: cvt(w->bf16) -> LN -> GEMM1(+silu split) -> GEMM2(+softplus) -> scan -> GEMM3(+resid)
// R2: GEMMs rewritten as barrier-free direct-from-global MFMA (no LDS). Rationale:
// K is only 256/384 (4-6 k-iters), so the m97 2-barrier LDS structure is ~90%
// vmcnt(0)-drain stall (R1 counters: MfmaUtil 4.6%). Fragments are 16B/lane
// contiguous -> load straight to VGPRs; weights are L2-resident (<=576KB).
#define B_  8
#define L_  4096
#define DM  256
#define DI  384
#define DS  8
#define M_  (B_*L_)   // 32768 tokens

typedef float f32x4 __attribute__((ext_vector_type(4)));
typedef short s16x8 __attribute__((ext_vector_type(8)));

__device__ __forceinline__ unsigned short f2bf(float f) {
  union { float f; uint32_t u; } v; v.f = f;
  uint32_t r = v.u + 0x7FFFu + ((v.u >> 16) & 1u);   // RNE
  return (unsigned short)(r >> 16);
}
__device__ __forceinline__ float bf2f(unsigned short h) {
  union { uint32_t u; float f; } v; v.u = ((uint32_t)h) << 16;
  return v.f;
}
__device__ __forceinline__ float silu_f(float x) { return x / (1.f + __expf(-x)); }

// ---------------- weight fp32 -> bf16 ----------------
__global__ __launch_bounds__(256) void cvt_kernel(
    const float* __restrict__ w0, const float* __restrict__ w1, const float* __restrict__ w2,
    unsigned short* __restrict__ o0, unsigned short* __restrict__ o1, unsigned short* __restrict__ o2) {
  int i = blockIdx.x * 256 + threadIdx.x;
  if (i < 3*DI*DM) o0[i] = f2bf(w0[i]);
  if (i < DI*DI)   o1[i] = f2bf(w1[i]);
  if (i < DM*DI)   o2[i] = f2bf(w2[i]);
}

// ---------------- layernorm: one wave per token ----------------
__global__ __launch_bounds__(256) void ln_kernel(
    const float* __restrict__ x, const float* __restrict__ gamma, const float* __restrict__ beta,
    unsigned short* __restrict__ xn) {
  int token = blockIdx.x * 4 + (threadIdx.x >> 6);
  int lane  = threadIdx.x & 63;
  const float4 v = *(const float4*)(x + (size_t)token*DM + lane*4);
  float s  = v.x + v.y + v.z + v.w;
  float ss = v.x*v.x + v.y*v.y + v.z*v.z + v.w*v.w;
  #pragma unroll
  for (int off = 32; off > 0; off >>= 1) {
    s  += __shfl_xor(s,  off, 64);
    ss += __shfl_xor(ss, off, 64);
  }
  float mean = s * (1.f/DM);
  float var  = ss * (1.f/DM) - mean*mean;
  float rstd = rsqrtf(var + 1e-5f);
  const float4 g = *(const float4*)(gamma + lane*4);
  const float4 b = *(const float4*)(beta  + lane*4);
  ushort4 o;
  o.x = f2bf((v.x - mean)*rstd*g.x + b.x);
  o.y = f2bf((v.y - mean)*rstd*g.y + b.y);
  o.z = f2bf((v.z - mean)*rstd*g.z + b.z);
  o.w = f2bf((v.w - mean)*rstd*g.w + b.w);
  *(ushort4*)(xn + (size_t)token*DM + lane*4) = o;
}

// ---------------- direct-from-global bf16 MFMA GEMM ----------------
// C[M,N] = A[M,K] @ Bw[N,K]^T (+ epilogue). 128x128 tile, 256 thr (2x2 waves,
// 64x64/wave, 4x4 of 16x16x32). No LDS, no barriers: lane (fr,fq) loads its
// A-fragment A[row=..+fr][k=kt*32+fq*8 ..+8] as one dwordx4 (wave covers
// 16 rows x 64 contiguous B -> line-coalesced). K fully unrolled.
template<int EPI, int KSTEPS>
__global__ __launch_bounds__(256, 2) void gemm_direct(
    const unsigned short* __restrict__ A,   // [M,K] bf16
    const unsigned short* __restrict__ Bw,  // [N,K] bf16 (weight rows = output cols)
    const float* __restrict__ bias,         // [N]
    unsigned short* __restrict__ o_xp, unsigned short* __restrict__ o_z,
    unsigned short* __restrict__ o_dtin,    // EPI=1
    unsigned short* __restrict__ o_bf,      // EPI=2
    const float* __restrict__ resid, float* __restrict__ o_f)  // EPI=3
{
  constexpr int K = KSTEPS * 32;
  const int t    = threadIdx.x;
  const int lane = t & 63;
  const int w    = t >> 6;
  const int wm   = (w & 1) * 64;
  const int wn   = (w >> 1) * 64;
  const int fr   = lane & 15;
  const int fq   = lane >> 4;
  const int mbase = blockIdx.x * 128;
  const int nbase = blockIdx.y * 128;

  const unsigned short* aptr[4];
  const unsigned short* bptr[4];
  #pragma unroll
  for (int mi = 0; mi < 4; ++mi)
    aptr[mi] = A  + (size_t)(mbase + wm + mi*16 + fr) * K + fq*8;
  #pragma unroll
  for (int ni = 0; ni < 4; ++ni)
    bptr[ni] = Bw + (size_t)(nbase + wn + ni*16 + fr) * K + fq*8;

  f32x4 acc[4][4];
  #pragma unroll
  for (int mi = 0; mi < 4; ++mi)
    #pragma unroll
    for (int ni = 0; ni < 4; ++ni) acc[mi][ni] = (f32x4){0.f, 0.f, 0.f, 0.f};

  #pragma unroll
  for (int kt = 0; kt < KSTEPS; ++kt) {
    s16x8 af[4], bfr[4];
    #pragma unroll
    for (int mi = 0; mi < 4; ++mi) af[mi]  = *(const s16x8*)(aptr[mi] + kt*32);
    #pragma unroll
    for (int ni = 0; ni < 4; ++ni) bfr[ni] = *(const s16x8*)(bptr[ni] + kt*32);
    #pragma unroll
    for (int mi = 0; mi < 4; ++mi)
      #pragma unroll
      for (int ni = 0; ni < 4; ++ni)
        acc[mi][ni] = __builtin_amdgcn_mfma_f32_16x16x32_bf16(af[mi], bfr[ni], acc[mi][ni], 0, 0, 0);
  }

  // epilogue: lane holds C[row=fq*4+r][col=fr] per 16x16 tile (m89-verified layout)
  #pragma unroll
  for (int ni = 0; ni < 4; ++ni) {
    int gn = nbase + wn + ni*16 + fr;
    float bv = bias[gn];
    #pragma unroll
    for (int mi = 0; mi < 4; ++mi) {
      int gm0 = mbase + wm + mi*16 + fq*4;
      #pragma unroll
      for (int r = 0; r < 4; ++r) {
        float c = acc[mi][ni][r] + bv;
        size_t gm = (size_t)(gm0 + r);
        if constexpr (EPI == 1) {
          if (gn < DI)            o_xp[gm*DI + gn]          = f2bf(silu_f(c));
          else if (gn < 2*DI)     o_z[gm*DI + (gn - DI)]    = f2bf(silu_f(c));
          else                    o_dtin[gm*DI + (gn-2*DI)] = f2bf(c);
        } else if constexpr (EPI == 2) {
          float sp = (c > 20.f) ? c : log1pf(__expf(c));
          o_bf[gm*DI + gn] = f2bf(sp);
        } else {
          o_f[gm*DM + gn] = c + resid[gm*DM + gn];
        }
      }
    }
  }
}

// ---------------- chunked selective scan ----------------
// one thread per (chunk, channel); h resets to 0 each 32-step chunk (faithful to ref)
__global__ __launch_bounds__(384) void scan_kernel(
    const unsigned short* __restrict__ xp, const unsigned short* __restrict__ dt,
    const unsigned short* __restrict__ zb, const float* __restrict__ A_log,
    const float* __restrict__ D_vec, unsigned short* __restrict__ yz) {
  int g  = blockIdx.x;      // 0..(M_/32-1)
  int di = threadIdx.x;     // 0..383
  size_t base = (size_t)g * 32 * DI + di;
  float a[DS];
  #pragma unroll
  for (int s = 0; s < DS; ++s) a[s] = -__expf(A_log[di*DS + s]);   // A = -exp(A_log)
  float Dv = D_vec[di];
  float h[DS] = {0.f,0.f,0.f,0.f,0.f,0.f,0.f,0.f};
  for (int tt = 0; tt < 32; ++tt) {
    size_t idx = base + (size_t)tt * DI;
    float xv  = bf2f(xp[idx]);
    float dtv = bf2f(dt[idx]);
    float y = 0.f;
    #pragma unroll
    for (int s = 0; s < DS; ++s) {
      h[s] = h[s] * __expf(dtv * a[s]) + xv;
      y += h[s];
    }
    float zv = bf2f(zb[idx]);
    yz[idx] = f2bf(y * zv + xv * Dv);
  }
}

extern "C" void kernel_launch(void* const* d_in, const int* in_sizes, int n_in,
                              void* d_out, int out_size, void* d_ws, size_t ws_size,
                              hipStream_t stream) {
  const float* x     = (const float*)d_in[0];
  const float* gamma = (const float*)d_in[1];
  const float* beta  = (const float*)d_in[2];
  const float* W_in  = (const float*)d_in[3];
  const float* b_in  = (const float*)d_in[4];
  const float* W_dt  = (const float*)d_in[5];
  const float* b_dt  = (const float*)d_in[6];
  const float* A_log = (const float*)d_in[7];
  const float* D_vec = (const float*)d_in[8];
  const float* W_out = (const float*)d_in[9];
  const float* b_out = (const float*)d_in[10];
  float* out = (float*)d_out;

  char* ws = (char*)d_ws;
  size_t off = 0;
  auto alloc = [&](size_t bytes) -> char* {
    char* p = ws + off; off += (bytes + 255) & ~(size_t)255; return p;
  };
  unsigned short* xn    = (unsigned short*)alloc((size_t)M_*DM*2);  // 16.8 MB
  unsigned short* xpb   = (unsigned short*)alloc((size_t)M_*DI*2);  // 25.2 MB
  unsigned short* zb    = (unsigned short*)alloc((size_t)M_*DI*2);
  unsigned short* dtin  = (unsigned short*)alloc((size_t)M_*DI*2);
  unsigned short* dtb   = (unsigned short*)alloc((size_t)M_*DI*2);
  unsigned short* yzb   = dtin;   // dtin dead after GEMM2 -> reuse for yz
  unsigned short* winb  = (unsigned short*)alloc((size_t)3*DI*DM*2);
  unsigned short* wdtb  = (unsigned short*)alloc((size_t)DI*DI*2);
  unsigned short* woutb = (unsigned short*)alloc((size_t)DM*DI*2);

  cvt_kernel<<<dim3((3*DI*DM + 255)/256), 256, 0, stream>>>(W_in, W_dt, W_out, winb, wdtb, woutb);
  ln_kernel<<<dim3(M_/4), 256, 0, stream>>>(x, gamma, beta, xn);
  // GEMM1: xn[M,256] @ W_in[1152,256]^T ; split cols -> silu(xp), silu(z), dtin
  gemm_direct<1, 8><<<dim3(M_/128, (3*DI)/128), 256, 0, stream>>>(
      xn, winb, b_in, xpb, zb, dtin, nullptr, nullptr, nullptr);
  // GEMM2: dtin[M,384] @ W_dt[384,384]^T ; softplus -> dt
  gemm_direct<2, 12><<<dim3(M_/128, DI/128), 256, 0, stream>>>(
      dtin, wdtb, b_dt, nullptr, nullptr, nullptr, dtb, nullptr, nullptr);
  // scan -> yz = y*z + xp*D
  scan_kernel<<<dim3(M_/32), DI, 0, stream>>>(xpb, dtb, zb, A_log, D_vec, yzb);
  // GEMM3: yz[M,384] @ W_out[256,384]^T + b_out + residual -> out (fp32)
  gemm_direct<3, 12><<<dim3(M_/128, DM/128), 256, 0, stream>>>(
      yzb, woutb, b_out, nullptr, nullptr, nullptr, nullptr, x, out);
}

// Round 3
// 310.624 us; speedup vs baseline: 1.0474x; 1.0474x over previous
//
#include <hip/hip_runtime.h>
#include <stdint.h>

// S6Layer on MI355X. B=8, L=4096, DM=256, DI=384, DS=8, CHUNK=32.
// R3: direct-from-global MFMA GEMM with EXPLICIT register double-buffer
// (R2 post-mortem: VGPR=72 -> compiler kept ~2 loads in flight -> latency-bound,
// MfmaUtil 7.5%). Now kt+1 fragments load before kt MFMAs => vmcnt(8) pipeline.
// bf16 epilogues stage through LDS for 256B-coalesced stores (R2 WRITE_SIZE
// was 114MB vs 75MB ideal from 2B scattered stores).
#define B_  8
#define L_  4096
#define DM  256
#define DI  384
#define DS  8
#define M_  (B_*L_)   // 32768 tokens

typedef float f32x4 __attribute__((ext_vector_type(4)));
typedef short s16x8 __attribute__((ext_vector_type(8)));

__device__ __forceinline__ unsigned short f2bf(float f) {
  union { float f; uint32_t u; } v; v.f = f;
  uint32_t r = v.u + 0x7FFFu + ((v.u >> 16) & 1u);   // RNE
  return (unsigned short)(r >> 16);
}
__device__ __forceinline__ float bf2f(unsigned short h) {
  union { uint32_t u; float f; } v; v.u = ((uint32_t)h) << 16;
  return v.f;
}
__device__ __forceinline__ float silu_f(float x) { return x / (1.f + __expf(-x)); }

// ---------------- weight fp32 -> bf16 ----------------
__global__ __launch_bounds__(256) void cvt_kernel(
    const float* __restrict__ w0, const float* __restrict__ w1, const float* __restrict__ w2,
    unsigned short* __restrict__ o0, unsigned short* __restrict__ o1, unsigned short* __restrict__ o2) {
  int i = blockIdx.x * 256 + threadIdx.x;
  if (i < 3*DI*DM) o0[i] = f2bf(w0[i]);
  if (i < DI*DI)   o1[i] = f2bf(w1[i]);
  if (i < DM*DI)   o2[i] = f2bf(w2[i]);
}

// ---------------- layernorm: one wave per token ----------------
__global__ __launch_bounds__(256) void ln_kernel(
    const float* __restrict__ x, const float* __restrict__ gamma, const float* __restrict__ beta,
    unsigned short* __restrict__ xn) {
  int token = blockIdx.x * 4 + (threadIdx.x >> 6);
  int lane  = threadIdx.x & 63;
  const float4 v = *(const float4*)(x + (size_t)token*DM + lane*4);
  float s  = v.x + v.y + v.z + v.w;
  float ss = v.x*v.x + v.y*v.y + v.z*v.z + v.w*v.w;
  #pragma unroll
  for (int off = 32; off > 0; off >>= 1) {
    s  += __shfl_xor(s,  off, 64);
    ss += __shfl_xor(ss, off, 64);
  }
  float mean = s * (1.f/DM);
  float var  = ss * (1.f/DM) - mean*mean;
  float rstd = rsqrtf(var + 1e-5f);
  const float4 g = *(const float4*)(gamma + lane*4);
  const float4 b = *(const float4*)(beta  + lane*4);
  ushort4 o;
  o.x = f2bf((v.x - mean)*rstd*g.x + b.x);
  o.y = f2bf((v.y - mean)*rstd*g.y + b.y);
  o.z = f2bf((v.z - mean)*rstd*g.z + b.z);
  o.w = f2bf((v.w - mean)*rstd*g.w + b.w);
  *(ushort4*)(xn + (size_t)token*DM + lane*4) = o;
}

// ---------------- pipelined direct-from-global bf16 MFMA GEMM ----------------
// C[M,N] = A[M,K] @ Bw[N,K]^T (+ epilogue). 128x128 tile, 256 thr (2x2 waves,
// 64x64/wave, 4x4 of 16x16x32). No barriers in K-loop; register double-buffer
// keeps 8 dwordx4 loads in flight behind every MFMA block.
template<int EPI, int KSTEPS>
__global__ __launch_bounds__(256, 3) void gemm_pipe(
    const unsigned short* __restrict__ A,   // [M,K] bf16
    const unsigned short* __restrict__ Bw,  // [N,K] bf16 (weight rows = output cols)
    const float* __restrict__ bias,         // [N]
    unsigned short* __restrict__ o_xp, unsigned short* __restrict__ o_z,
    unsigned short* __restrict__ o_dtin,    // EPI=1
    unsigned short* __restrict__ o_bf,      // EPI=2
    const float* __restrict__ resid, float* __restrict__ o_f)  // EPI=3
{
  constexpr int K = KSTEPS * 32;
  const int t    = threadIdx.x;
  const int lane = t & 63;
  const int w    = t >> 6;
  const int wm   = (w & 1) * 64;
  const int wn   = (w >> 1) * 64;
  const int fr   = lane & 15;
  const int fq   = lane >> 4;
  const int mbase = blockIdx.x * 128;
  const int nbase = blockIdx.y * 128;

  const unsigned short* aptr[4];
  const unsigned short* bptr[4];
  #pragma unroll
  for (int mi = 0; mi < 4; ++mi)
    aptr[mi] = A  + (size_t)(mbase + wm + mi*16 + fr) * K + fq*8;
  #pragma unroll
  for (int ni = 0; ni < 4; ++ni)
    bptr[ni] = Bw + (size_t)(nbase + wn + ni*16 + fr) * K + fq*8;

  f32x4 acc[4][4];
  #pragma unroll
  for (int mi = 0; mi < 4; ++mi)
    #pragma unroll
    for (int ni = 0; ni < 4; ++ni) acc[mi][ni] = (f32x4){0.f, 0.f, 0.f, 0.f};

  // register double-buffered fragment pipeline
  s16x8 afb[2][4], bfb[2][4];
  #pragma unroll
  for (int mi = 0; mi < 4; ++mi) afb[0][mi] = *(const s16x8*)(aptr[mi]);
  #pragma unroll
  for (int ni = 0; ni < 4; ++ni) bfb[0][ni] = *(const s16x8*)(bptr[ni]);

  #pragma unroll
  for (int kt = 0; kt < KSTEPS; ++kt) {
    const int cur = kt & 1, nxt = cur ^ 1;
    if (kt + 1 < KSTEPS) {
      #pragma unroll
      for (int mi = 0; mi < 4; ++mi) afb[nxt][mi] = *(const s16x8*)(aptr[mi] + (kt+1)*32);
      #pragma unroll
      for (int ni = 0; ni < 4; ++ni) bfb[nxt][ni] = *(const s16x8*)(bptr[ni] + (kt+1)*32);
    }
    #pragma unroll
    for (int mi = 0; mi < 4; ++mi)
      #pragma unroll
      for (int ni = 0; ni < 4; ++ni)
        acc[mi][ni] = __builtin_amdgcn_mfma_f32_16x16x32_bf16(afb[cur][mi], bfb[cur][ni], acc[mi][ni], 0, 0, 0);
  }

  // ---------------- epilogue ----------------
  // MFMA C layout per 16x16 tile: col = fr, row = fq*4 + r (m89-verified)
  if constexpr (EPI == 3) {
    // fp32 out + bias + residual; 16 lanes x 4B = 64B coalesced: direct store
    #pragma unroll
    for (int ni = 0; ni < 4; ++ni) {
      int gn = nbase + wn + ni*16 + fr;
      float bv = bias[gn];
      #pragma unroll
      for (int mi = 0; mi < 4; ++mi) {
        int gm0 = mbase + wm + mi*16 + fq*4;
        #pragma unroll
        for (int r = 0; r < 4; ++r) {
          size_t gm = (size_t)(gm0 + r);
          o_f[gm*DM + gn] = acc[mi][ni][r] + bv + resid[gm*DM + gn];
        }
      }
    }
  } else {
    // bf16 outs: activation in-register, stage tile in LDS (pad 136: <=2-way
    // bank aliasing on both write and b128 readback = free per m136), then
    // 16B/lane row-major readback -> 256B-contiguous global stores.
    __shared__ unsigned short sC[128 * 136];
    const bool do_silu = (EPI == 1) && (blockIdx.y < 6);   // panels 0-5 = xp,z
    #pragma unroll
    for (int ni = 0; ni < 4; ++ni) {
      int cn = wn + ni*16 + fr;
      float bv = bias[nbase + cn];
      #pragma unroll
      for (int mi = 0; mi < 4; ++mi) {
        int rm0 = wm + mi*16 + fq*4;
        #pragma unroll
        for (int r = 0; r < 4; ++r) {
          float c = acc[mi][ni][r] + bv;
          if constexpr (EPI == 1) { if (do_silu) c = silu_f(c); }
          else                    { c = (c > 20.f) ? c : log1pf(__expf(c)); }
          sC[(rm0 + r)*136 + cn] = f2bf(c);
        }
      }
    }
    __syncthreads();
    unsigned short* dst;
    int colbase;
    if constexpr (EPI == 1) {
      int p = blockIdx.y;                       // 0..8
      dst = (p < 3) ? o_xp : (p < 6) ? o_z : o_dtin;
      colbase = (p % 3) * 128;
    } else {
      dst = o_bf; colbase = nbase;
    }
    const int rr = t >> 4, cc = (t & 15) * 8;
    #pragma unroll
    for (int it = 0; it < 8; ++it) {
      int row = rr + it*16;
      s16x8 v = *(const s16x8*)(sC + row*136 + cc);
      *(s16x8*)(dst + (size_t)(mbase + row)*DI + colbase + cc) = v;
    }
  }
}

// ---------------- chunked selective scan ----------------
// one thread per (chunk, channel); h resets to 0 each 32-step chunk (faithful to ref)
__global__ __launch_bounds__(384) void scan_kernel(
    const unsigned short* __restrict__ xp, const unsigned short* __restrict__ dt,
    const unsigned short* __restrict__ zb, const float* __restrict__ A_log,
    const float* __restrict__ D_vec, unsigned short* __restrict__ yz) {
  int g  = blockIdx.x;      // 0..(M_/32-1)
  int di = threadIdx.x;     // 0..383
  size_t base = (size_t)g * 32 * DI + di;
  float a[DS];
  #pragma unroll
  for (int s = 0; s < DS; ++s) a[s] = -__expf(A_log[di*DS + s]);   // A = -exp(A_log)
  float Dv = D_vec[di];
  float h[DS] = {0.f,0.f,0.f,0.f,0.f,0.f,0.f,0.f};
  for (int tt = 0; tt < 32; ++tt) {
    size_t idx = base + (size_t)tt * DI;
    float xv  = bf2f(xp[idx]);
    float dtv = bf2f(dt[idx]);
    float y = 0.f;
    #pragma unroll
    for (int s = 0; s < DS; ++s) {
      h[s] = h[s] * __expf(dtv * a[s]) + xv;
      y += h[s];
    }
    float zv = bf2f(zb[idx]);
    yz[idx] = f2bf(y * zv + xv * Dv);
  }
}

extern "C" void kernel_launch(void* const* d_in, const int* in_sizes, int n_in,
                              void* d_out, int out_size, void* d_ws, size_t ws_size,
                              hipStream_t stream) {
  const float* x     = (const float*)d_in[0];
  const float* gamma = (const float*)d_in[1];
  const float* beta  = (const float*)d_in[2];
  const float* W_in  = (const float*)d_in[3];
  const float* b_in  = (const float*)d_in[4];
  const float* W_dt  = (const float*)d_in[5];
  const float* b_dt  = (const float*)d_in[6];
  const float* A_log = (const float*)d_in[7];
  const float* D_vec = (const float*)d_in[8];
  const float* W_out = (const float*)d_in[9];
  const float* b_out = (const float*)d_in[10];
  float* out = (float*)d_out;

  char* ws = (char*)d_ws;
  size_t off = 0;
  auto alloc = [&](size_t bytes) -> char* {
    char* p = ws + off; off += (bytes + 255) & ~(size_t)255; return p;
  };
  unsigned short* xn    = (unsigned short*)alloc((size_t)M_*DM*2);  // 16.8 MB
  unsigned short* xpb   = (unsigned short*)alloc((size_t)M_*DI*2);  // 25.2 MB
  unsigned short* zb    = (unsigned short*)alloc((size_t)M_*DI*2);
  unsigned short* dtin  = (unsigned short*)alloc((size_t)M_*DI*2);
  unsigned short* dtb   = (unsigned short*)alloc((size_t)M_*DI*2);
  unsigned short* yzb   = dtin;   // dtin dead after GEMM2 -> reuse for yz
  unsigned short* winb  = (unsigned short*)alloc((size_t)3*DI*DM*2);
  unsigned short* wdtb  = (unsigned short*)alloc((size_t)DI*DI*2);
  unsigned short* woutb = (unsigned short*)alloc((size_t)DM*DI*2);

  cvt_kernel<<<dim3((3*DI*DM + 255)/256), 256, 0, stream>>>(W_in, W_dt, W_out, winb, wdtb, woutb);
  ln_kernel<<<dim3(M_/4), 256, 0, stream>>>(x, gamma, beta, xn);
  // GEMM1: xn[M,256] @ W_in[1152,256]^T ; split cols -> silu(xp), silu(z), dtin
  gemm_pipe<1, 8><<<dim3(M_/128, (3*DI)/128), 256, 0, stream>>>(
      xn, winb, b_in, xpb, zb, dtin, nullptr, nullptr, nullptr);
  // GEMM2: dtin[M,384] @ W_dt[384,384]^T ; softplus -> dt
  gemm_pipe<2, 12><<<dim3(M_/128, DI/128), 256, 0, stream>>>(
      dtin, wdtb, b_dt, nullptr, nullptr, nullptr, dtb, nullptr, nullptr);
  // scan -> yz = y*z + xp*D
  scan_kernel<<<dim3(M_/32), DI, 0, stream>>>(xpb, dtb, zb, A_log, D_vec, yzb);
  // GEMM3: yz[M,384] @ W_out[256,384]^T + b_out + residual -> out (fp32)
  gemm_pipe<3, 12><<<dim3(M_/128, DM/128), 256, 0, stream>>>(
      yzb, woutb, b_out, nullptr, nullptr, nullptr, nullptr, x, out);
}

// Round 4
// 268.672 us; speedup vs baseline: 1.2109x; 1.1561x over previous
//
#include <hip/hip_runtime.h>
#include <stdint.h>

// S6Layer on MI355X. B=8, L=4096, DM=256, DI=384, DS=8, CHUNK=32.
// R4: GEMM = B-panel-in-LDS (staged once, zero K-loop barriers) + tall block
// (256M x 64N, 4 waves split M, weights reused 4x from LDS) + 3-buffer A
// register pipeline with 2-kstep lookahead.
// R3 post-mortem: VGPR=64 proved the compiler sank the A/B prefetch loads to
// point-of-use -> serial latency (MfmaUtil 8.4%). Moving B to LDS halves the
// global-load pressure and the A pipeline now has no competing B loads.
#define B_  8
#define L_  4096
#define DM  256
#define DI  384
#define DS  8
#define M_  (B_*L_)   // 32768 tokens

typedef float f32x4 __attribute__((ext_vector_type(4)));
typedef short s16x8 __attribute__((ext_vector_type(8)));

__device__ __forceinline__ unsigned short f2bf(float f) {
  union { float f; uint32_t u; } v; v.f = f;
  uint32_t r = v.u + 0x7FFFu + ((v.u >> 16) & 1u);   // RNE
  return (unsigned short)(r >> 16);
}
__device__ __forceinline__ float bf2f(unsigned short h) {
  union { uint32_t u; float f; } v; v.u = ((uint32_t)h) << 16;
  return v.f;
}
__device__ __forceinline__ float silu_f(float x) { return x / (1.f + __expf(-x)); }

// ---------------- weight fp32 -> bf16 ----------------
__global__ __launch_bounds__(256) void cvt_kernel(
    const float* __restrict__ w0, const float* __restrict__ w1, const float* __restrict__ w2,
    unsigned short* __restrict__ o0, unsigned short* __restrict__ o1, unsigned short* __restrict__ o2) {
  int i = blockIdx.x * 256 + threadIdx.x;
  if (i < 3*DI*DM) o0[i] = f2bf(w0[i]);
  if (i < DI*DI)   o1[i] = f2bf(w1[i]);
  if (i < DM*DI)   o2[i] = f2bf(w2[i]);
}

// ---------------- layernorm: one wave per token ----------------
__global__ __launch_bounds__(256) void ln_kernel(
    const float* __restrict__ x, const float* __restrict__ gamma, const float* __restrict__ beta,
    unsigned short* __restrict__ xn) {
  int token = blockIdx.x * 4 + (threadIdx.x >> 6);
  int lane  = threadIdx.x & 63;
  const float4 v = *(const float4*)(x + (size_t)token*DM + lane*4);
  float s  = v.x + v.y + v.z + v.w;
  float ss = v.x*v.x + v.y*v.y + v.z*v.z + v.w*v.w;
  #pragma unroll
  for (int off = 32; off > 0; off >>= 1) {
    s  += __shfl_xor(s,  off, 64);
    ss += __shfl_xor(ss, off, 64);
  }
  float mean = s * (1.f/DM);
  float var  = ss * (1.f/DM) - mean*mean;
  float rstd = rsqrtf(var + 1e-5f);
  const float4 g = *(const float4*)(gamma + lane*4);
  const float4 b = *(const float4*)(beta  + lane*4);
  ushort4 o;
  o.x = f2bf((v.x - mean)*rstd*g.x + b.x);
  o.y = f2bf((v.y - mean)*rstd*g.y + b.y);
  o.z = f2bf((v.z - mean)*rstd*g.z + b.z);
  o.w = f2bf((v.w - mean)*rstd*g.w + b.w);
  *(ushort4*)(xn + (size_t)token*DM + lane*4) = o;
}

// ---------------- B-in-LDS MFMA GEMM ----------------
// C[M,N] = A[M,K] @ Bw[N,K]^T. Block: 256 thr (4 waves), tile 256M x 64N.
// Wave w owns rows w*64..w*64+63, all 64 N-cols; acc 4x4 of 16x16x32 tiles.
// B panel (64 rows of Bw x K) staged to LDS once via global_load_lds(16B),
// global-side XOR swizzle (low 3 bits of chunk) so ds_read_b128 spreads
// evenly over banks. K-loop barrier-free; A via 3-buffer reg pipeline.
template<int EPI, int KSTEPS>
__global__ __launch_bounds__(256, 3) void gemm_bn(
    const unsigned short* __restrict__ A,   // [M,K] bf16
    const unsigned short* __restrict__ Bw,  // [N,K] bf16
    const float* __restrict__ bias,         // [N]
    unsigned short* __restrict__ o_xp, unsigned short* __restrict__ o_z,
    unsigned short* __restrict__ o_dtin,    // EPI=1
    unsigned short* __restrict__ o_bf,      // EPI=2
    const float* __restrict__ resid, float* __restrict__ o_f)  // EPI=3
{
  constexpr int K    = KSTEPS * 32;
  constexpr int CPR  = K / 8;              // 16B chunks per B row
  constexpr int BCH  = 64 * CPR;           // total B chunks (multiple of 256)
  constexpr int SB_E = 64 * K;             // B elems in LDS
  constexpr int SC_E = 256 * 64;           // epilogue C tile elems
  constexpr int SM_E = (SB_E > SC_E) ? SB_E : SC_E;
  __shared__ unsigned short smem[SM_E];

  const int t    = threadIdx.x;
  const int lane = t & 63;
  const int w    = t >> 6;
  const int fr   = lane & 15;
  const int fq   = lane >> 4;
  const int mbase = blockIdx.x * 256;
  const int nbase = blockIdx.y * 64;
  const int wm   = w * 64;

  // ---- stage B panel: LDS slot c holds global chunk swizzle(c) ----
  #pragma unroll
  for (int i = 0; i < BCH/256; ++i) {
    int c   = i*256 + t;
    int row = c / CPR;
    int j   = c - row*CPR;
    int jp  = (j & ~7) | ((j & 7) ^ (row & 7));
    const unsigned short* g = Bw + (size_t)(nbase + row)*K + jp*8;
    __builtin_amdgcn_global_load_lds(
        (__attribute__((address_space(1))) void*)g,
        (__attribute__((address_space(3))) void*)(smem + c*8), 16, 0, 0);
  }

  // ---- A fragment pointers + 2-step lookahead preload ----
  const unsigned short* aptr[4];
  #pragma unroll
  for (int mi = 0; mi < 4; ++mi)
    aptr[mi] = A + (size_t)(mbase + wm + mi*16 + fr) * K + fq*8;

  s16x8 afb[3][4];
  #pragma unroll
  for (int mi = 0; mi < 4; ++mi) afb[0][mi] = *(const s16x8*)(aptr[mi]);
  #pragma unroll
  for (int mi = 0; mi < 4; ++mi) afb[1][mi] = *(const s16x8*)(aptr[mi] + 32);

  f32x4 acc[4][4];
  #pragma unroll
  for (int mi = 0; mi < 4; ++mi)
    #pragma unroll
    for (int ni = 0; ni < 4; ++ni) acc[mi][ni] = (f32x4){0.f, 0.f, 0.f, 0.f};

  __syncthreads();   // B staged (drains all vmcnt incl. A preloads, once)

  // ---- barrier-free K-loop ----
  #pragma unroll
  for (int kt = 0; kt < KSTEPS; ++kt) {
    if (kt + 2 < KSTEPS) {
      #pragma unroll
      for (int mi = 0; mi < 4; ++mi)
        afb[(kt+2)%3][mi] = *(const s16x8*)(aptr[mi] + (kt+2)*32);
    }
    s16x8 bfr[4];
    #pragma unroll
    for (int ni = 0; ni < 4; ++ni) {
      int r    = ni*16 + fr;
      int j    = kt*4 + fq;
      int slot = (j & ~7) | ((j & 7) ^ (r & 7));
      bfr[ni]  = *(const s16x8*)(smem + r*K + slot*8);
    }
    #pragma unroll
    for (int mi = 0; mi < 4; ++mi)
      #pragma unroll
      for (int ni = 0; ni < 4; ++ni)
        acc[mi][ni] = __builtin_amdgcn_mfma_f32_16x16x32_bf16(afb[kt%3][mi], bfr[ni], acc[mi][ni], 0, 0, 0);
  }

  // ---- epilogue: C layout per 16x16 tile: col=fr, row=fq*4+r (m89) ----
  if constexpr (EPI == 3) {
    #pragma unroll
    for (int ni = 0; ni < 4; ++ni) {
      int gn = nbase + ni*16 + fr;
      float bv = bias[gn];
      #pragma unroll
      for (int mi = 0; mi < 4; ++mi) {
        int gm0 = mbase + wm + mi*16 + fq*4;
        #pragma unroll
        for (int r = 0; r < 4; ++r) {
          size_t gm = (size_t)(gm0 + r);
          o_f[gm*DM + gn] = acc[mi][ni][r] + bv + resid[gm*DM + gn];
        }
      }
    }
  } else {
    __syncthreads();   // everyone done reading B from smem
    const bool do_silu = (EPI == 1) && (blockIdx.y < 12);   // panels 0-5 xp, 6-11 z
    #pragma unroll
    for (int ni = 0; ni < 4; ++ni) {
      int cn = ni*16 + fr;
      float bv = bias[nbase + cn];
      #pragma unroll
      for (int mi = 0; mi < 4; ++mi) {
        int rm0 = wm + mi*16 + fq*4;
        #pragma unroll
        for (int r = 0; r < 4; ++r) {
          float c = acc[mi][ni][r] + bv;
          if constexpr (EPI == 1) { if (do_silu) c = silu_f(c); }
          else                    { c = (c > 20.f) ? c : log1pf(__expf(c)); }
          smem[(rm0 + r)*64 + cn] = f2bf(c);
        }
      }
    }
    __syncthreads();
    unsigned short* dst;
    int colbase;
    if constexpr (EPI == 1) {
      int p = blockIdx.y;                       // 0..17
      dst = (p < 6) ? o_xp : (p < 12) ? o_z : o_dtin;
      colbase = (p % 6) * 64;
    } else {
      dst = o_bf; colbase = nbase;
    }
    const int rr = t >> 3, cc = (t & 7) * 8;
    #pragma unroll
    for (int it = 0; it < 8; ++it) {
      int row = rr + it*32;
      s16x8 v = *(const s16x8*)(smem + row*64 + cc);
      *(s16x8*)(dst + (size_t)(mbase + row)*DI + colbase + cc) = v;
    }
  }
}

// ---------------- chunked selective scan ----------------
__global__ __launch_bounds__(384) void scan_kernel(
    const unsigned short* __restrict__ xp, const unsigned short* __restrict__ dt,
    const unsigned short* __restrict__ zb, const float* __restrict__ A_log,
    const float* __restrict__ D_vec, unsigned short* __restrict__ yz) {
  int g  = blockIdx.x;
  int di = threadIdx.x;
  size_t base = (size_t)g * 32 * DI + di;
  float a[DS];
  #pragma unroll
  for (int s = 0; s < DS; ++s) a[s] = -__expf(A_log[di*DS + s]);
  float Dv = D_vec[di];
  float h[DS] = {0.f,0.f,0.f,0.f,0.f,0.f,0.f,0.f};
  for (int tt = 0; tt < 32; ++tt) {
    size_t idx = base + (size_t)tt * DI;
    float xv  = bf2f(xp[idx]);
    float dtv = bf2f(dt[idx]);
    float y = 0.f;
    #pragma unroll
    for (int s = 0; s < DS; ++s) {
      h[s] = h[s] * __expf(dtv * a[s]) + xv;
      y += h[s];
    }
    float zv = bf2f(zb[idx]);
    yz[idx] = f2bf(y * zv + xv * Dv);
  }
}

extern "C" void kernel_launch(void* const* d_in, const int* in_sizes, int n_in,
                              void* d_out, int out_size, void* d_ws, size_t ws_size,
                              hipStream_t stream) {
  const float* x     = (const float*)d_in[0];
  const float* gamma = (const float*)d_in[1];
  const float* beta  = (const float*)d_in[2];
  const float* W_in  = (const float*)d_in[3];
  const float* b_in  = (const float*)d_in[4];
  const float* W_dt  = (const float*)d_in[5];
  const float* b_dt  = (const float*)d_in[6];
  const float* A_log = (const float*)d_in[7];
  const float* D_vec = (const float*)d_in[8];
  const float* W_out = (const float*)d_in[9];
  const float* b_out = (const float*)d_in[10];
  float* out = (float*)d_out;

  char* ws = (char*)d_ws;
  size_t off = 0;
  auto alloc = [&](size_t bytes) -> char* {
    char* p = ws + off; off += (bytes + 255) & ~(size_t)255; return p;
  };
  unsigned short* xn    = (unsigned short*)alloc((size_t)M_*DM*2);
  unsigned short* xpb   = (unsigned short*)alloc((size_t)M_*DI*2);
  unsigned short* zb    = (unsigned short*)alloc((size_t)M_*DI*2);
  unsigned short* dtin  = (unsigned short*)alloc((size_t)M_*DI*2);
  unsigned short* dtb   = (unsigned short*)alloc((size_t)M_*DI*2);
  unsigned short* yzb   = dtin;   // dtin dead after GEMM2 -> reuse for yz
  unsigned short* winb  = (unsigned short*)alloc((size_t)3*DI*DM*2);
  unsigned short* wdtb  = (unsigned short*)alloc((size_t)DI*DI*2);
  unsigned short* woutb = (unsigned short*)alloc((size_t)DM*DI*2);

  cvt_kernel<<<dim3((3*DI*DM + 255)/256), 256, 0, stream>>>(W_in, W_dt, W_out, winb, wdtb, woutb);
  ln_kernel<<<dim3(M_/4), 256, 0, stream>>>(x, gamma, beta, xn);
  // GEMM1: xn[M,256] @ W_in[1152,256]^T -> silu(xp), silu(z), dtin
  gemm_bn<1, 8><<<dim3(M_/256, (3*DI)/64), 256, 0, stream>>>(
      xn, winb, b_in, xpb, zb, dtin, nullptr, nullptr, nullptr);
  // GEMM2: dtin[M,384] @ W_dt[384,384]^T ; softplus -> dt
  gemm_bn<2, 12><<<dim3(M_/256, DI/64), 256, 0, stream>>>(
      dtin, wdtb, b_dt, nullptr, nullptr, nullptr, dtb, nullptr, nullptr);
  // scan -> yz = y*z + xp*D
  scan_kernel<<<dim3(M_/32), DI, 0, stream>>>(xpb, dtb, zb, A_log, D_vec, yzb);
  // GEMM3: yz[M,384] @ W_out[256,384]^T + b_out + residual -> out (fp32)
  gemm_bn<3, 12><<<dim3(M_/256, DM/64), 256, 0, stream>>>(
      yzb, woutb, b_out, nullptr, nullptr, nullptr, nullptr, x, out);
}

// Round 5
// 240.219 us; speedup vs baseline: 1.3543x; 1.1184x over previous
//
#include <hip/hip_runtime.h>
#include <stdint.h>

// S6Layer on MI355X. B=8, L=4096, DM=256, DI=384, DS=8, CHUNK=32.
// R5 GEMM: weights-stationary B panel in LDS (one barrier) + per-wave-private
// A staging via global_load_lds double-buffer with EXPLICIT s_waitcnt vmcnt(N).
// Rationale: R2-R4 proved the compiler sinks register prefetch (VGPR=64..76,
// MfmaUtil ~5-8%). global_load_lds has no dest VGPR -> cannot be sunk; the
// explicit vmcnt wait gives AITER-style never-drain pipelining per wave with
// zero K-loop barriers. Epilogue LDS staging pad 72 (R4: 983k bank conflicts
// at stride 64).
#define B_  8
#define L_  4096
#define DM  256
#define DI  384
#define DS  8
#define M_  (B_*L_)   // 32768 tokens

typedef float f32x4 __attribute__((ext_vector_type(4)));
typedef short s16x8 __attribute__((ext_vector_type(8)));

#define AS1(p) ((__attribute__((address_space(1))) void*)(p))
#define AS3(p) ((__attribute__((address_space(3))) void*)(p))

__device__ __forceinline__ unsigned short f2bf(float f) {
  union { float f; uint32_t u; } v; v.f = f;
  uint32_t r = v.u + 0x7FFFu + ((v.u >> 16) & 1u);   // RNE
  return (unsigned short)(r >> 16);
}
__device__ __forceinline__ float bf2f(unsigned short h) {
  union { uint32_t u; float f; } v; v.u = ((uint32_t)h) << 16;
  return v.f;
}
__device__ __forceinline__ float silu_f(float x) { return x / (1.f + __expf(-x)); }

// ---------------- weight fp32 -> bf16 ----------------
__global__ __launch_bounds__(256) void cvt_kernel(
    const float* __restrict__ w0, const float* __restrict__ w1, const float* __restrict__ w2,
    unsigned short* __restrict__ o0, unsigned short* __restrict__ o1, unsigned short* __restrict__ o2) {
  int i = blockIdx.x * 256 + threadIdx.x;
  if (i < 3*DI*DM) o0[i] = f2bf(w0[i]);
  if (i < DI*DI)   o1[i] = f2bf(w1[i]);
  if (i < DM*DI)   o2[i] = f2bf(w2[i]);
}

// ---------------- layernorm: one wave per token ----------------
__global__ __launch_bounds__(256) void ln_kernel(
    const float* __restrict__ x, const float* __restrict__ gamma, const float* __restrict__ beta,
    unsigned short* __restrict__ xn) {
  int token = blockIdx.x * 4 + (threadIdx.x >> 6);
  int lane  = threadIdx.x & 63;
  const float4 v = *(const float4*)(x + (size_t)token*DM + lane*4);
  float s  = v.x + v.y + v.z + v.w;
  float ss = v.x*v.x + v.y*v.y + v.z*v.z + v.w*v.w;
  #pragma unroll
  for (int off = 32; off > 0; off >>= 1) {
    s  += __shfl_xor(s,  off, 64);
    ss += __shfl_xor(ss, off, 64);
  }
  float mean = s * (1.f/DM);
  float var  = ss * (1.f/DM) - mean*mean;
  float rstd = rsqrtf(var + 1e-5f);
  const float4 g = *(const float4*)(gamma + lane*4);
  const float4 b = *(const float4*)(beta  + lane*4);
  ushort4 o;
  o.x = f2bf((v.x - mean)*rstd*g.x + b.x);
  o.y = f2bf((v.y - mean)*rstd*g.y + b.y);
  o.z = f2bf((v.z - mean)*rstd*g.z + b.z);
  o.w = f2bf((v.w - mean)*rstd*g.w + b.w);
  *(ushort4*)(xn + (size_t)token*DM + lane*4) = o;
}

// ---------------- weights-stationary MFMA GEMM, per-wave async A pipeline ----
// C[M,N] = A[M,K] @ Bw[N,K]^T. Block: 256 thr (4 waves), tile 128M x 64N;
// wave w owns rows w*32..w*32+31 (2 mi tiles) x all 64 N (4 ni tiles).
// LDS: B panel 64xK (swizzled 16B chunks, uniform 8-lanes/bank-quad on b128
// reads) + per-wave A double-buffer (2 x 2KB; chunk = 32 rows x 32 k).
// K-loop: issue chunk kt+1 (2x global_load_lds, no dest VGPR), s_waitcnt
// vmcnt(2) -> chunk kt resident, ds_read frags, 8 MFMAs. No barriers.
template<int EPI, int KSTEPS>
__global__ __launch_bounds__(256, 2) void gemm_ws(
    const unsigned short* __restrict__ A,   // [M,K] bf16
    const unsigned short* __restrict__ Bw,  // [N,K] bf16
    const float* __restrict__ bias,         // [N]
    unsigned short* __restrict__ o_xp, unsigned short* __restrict__ o_z,
    unsigned short* __restrict__ o_dtin,    // EPI=1
    unsigned short* __restrict__ o_bf,      // EPI=2
    const float* __restrict__ resid, float* __restrict__ o_f)  // EPI=3
{
  constexpr int K    = KSTEPS * 32;
  constexpr int CPR  = K / 8;               // 16B chunks per B row
  constexpr int SM_E = 64*K + 8192;         // B panel + 4 waves x 2 bufs x 1024 elems
  __shared__ unsigned short smem[SM_E];     // 64KB (K=384) / 48KB (K=256)
  unsigned short* sB = smem;

  const int t    = threadIdx.x;
  const int lane = t & 63;
  const int w    = t >> 6;
  const int fr   = lane & 15;
  const int fq   = lane >> 4;
  const int mbase = blockIdx.x * 128;
  const int nbase = blockIdx.y * 64;
  const int wm   = w * 32;
  unsigned short* sAw = smem + 64*K + w*2048;   // wave-private: 2 bufs x 1024 elems

  // ---- stage B panel (once): LDS slot c holds swizzled global chunk ----
  #pragma unroll
  for (int i = 0; i < (64*CPR)/256; ++i) {
    int c   = i*256 + t;
    int row = c / CPR;
    int j   = c - row*CPR;
    int jp  = (j & ~7) | ((j & 7) ^ (row & 7));
    __builtin_amdgcn_global_load_lds(AS1(Bw + (size_t)(nbase + row)*K + jp*8),
                                     AS3(sB + c*8), 16, 0, 0);
  }

  // ---- A global pointers: instr i covers rows i*16+(lane>>2), 16B chunk lane&3
  const unsigned short* gA[2];
  #pragma unroll
  for (int i = 0; i < 2; ++i)
    gA[i] = A + (size_t)(mbase + wm + i*16 + (lane >> 2)) * K + (lane & 3)*8;

  // preload chunk 0 into buf 0 (HW scatters lane -> +lane*16B)
  #pragma unroll
  for (int i = 0; i < 2; ++i)
    __builtin_amdgcn_global_load_lds(AS1(gA[i]), AS3(sAw + i*512), 16, 0, 0);

  f32x4 acc[2][4];
  #pragma unroll
  for (int mi = 0; mi < 2; ++mi)
    #pragma unroll
    for (int ni = 0; ni < 4; ++ni) acc[mi][ni] = (f32x4){0.f, 0.f, 0.f, 0.f};

  __syncthreads();   // B (and chunk0) resident; only barrier before epilogue

  #pragma unroll
  for (int kt = 0; kt < KSTEPS; ++kt) {
    if (kt + 1 < KSTEPS) {
      unsigned short* dstb = sAw + ((kt+1) & 1)*1024;
      #pragma unroll
      for (int i = 0; i < 2; ++i)
        __builtin_amdgcn_global_load_lds(AS1(gA[i] + (kt+1)*32), AS3(dstb + i*512), 16, 0, 0);
      __builtin_amdgcn_s_waitcnt(0xF72);   // vmcnt(2): chunk kt retired, kt+1 in flight
    } else {
      __builtin_amdgcn_s_waitcnt(0xF70);   // vmcnt(0): last chunk resident
    }
    const unsigned short* rbuf = sAw + (kt & 1)*1024;
    s16x8 af[2], bfr[4];
    #pragma unroll
    for (int mi = 0; mi < 2; ++mi)
      af[mi] = *(const s16x8*)(rbuf + mi*512 + fr*32 + fq*8);
    #pragma unroll
    for (int ni = 0; ni < 4; ++ni) {
      int r    = ni*16 + fr;
      int j    = kt*4 + fq;
      int slot = (j & ~7) | ((j & 7) ^ (r & 7));
      bfr[ni]  = *(const s16x8*)(sB + r*K + slot*8);
    }
    #pragma unroll
    for (int mi = 0; mi < 2; ++mi)
      #pragma unroll
      for (int ni = 0; ni < 4; ++ni)
        acc[mi][ni] = __builtin_amdgcn_mfma_f32_16x16x32_bf16(af[mi], bfr[ni], acc[mi][ni], 0, 0, 0);
  }

  // ---- epilogue: C layout per 16x16 tile: col=fr, row=fq*4+r (m89) ----
  if constexpr (EPI == 3) {
    #pragma unroll
    for (int ni = 0; ni < 4; ++ni) {
      int gn = nbase + ni*16 + fr;
      float bv = bias[gn];
      #pragma unroll
      for (int mi = 0; mi < 2; ++mi) {
        int gm0 = mbase + wm + mi*16 + fq*4;
        #pragma unroll
        for (int r = 0; r < 4; ++r) {
          size_t gm = (size_t)(gm0 + r);
          o_f[gm*DM + gn] = acc[mi][ni][r] + bv + resid[gm*DM + gn];
        }
      }
    }
  } else {
    __syncthreads();   // all waves done with sB/sA -> reuse for C staging
    const bool do_silu = (EPI == 1) && (blockIdx.y < 12);   // panels 0-5 xp, 6-11 z
    // stage with pad-72 row stride (144B == 4 mod 32 banks -> ~2-way on writes)
    #pragma unroll
    for (int ni = 0; ni < 4; ++ni) {
      int cn = ni*16 + fr;
      float bv = bias[nbase + cn];
      #pragma unroll
      for (int mi = 0; mi < 2; ++mi) {
        int rm0 = wm + mi*16 + fq*4;
        #pragma unroll
        for (int r = 0; r < 4; ++r) {
          float c = acc[mi][ni][r] + bv;
          if constexpr (EPI == 1) { if (do_silu) c = silu_f(c); }
          else                    { c = (c > 20.f) ? c : log1pf(__expf(c)); }
          smem[(rm0 + r)*72 + cn] = f2bf(c);
        }
      }
    }
    __syncthreads();
    unsigned short* dst;
    int colbase;
    if constexpr (EPI == 1) {
      int p = blockIdx.y;                       // 0..17
      dst = (p < 6) ? o_xp : (p < 12) ? o_z : o_dtin;
      colbase = (p % 6) * 64;
    } else {
      dst = o_bf; colbase = nbase;
    }
    const int rr = t >> 3, cc = (t & 7) * 8;
    #pragma unroll
    for (int it = 0; it < 4; ++it) {
      int row = rr + it*32;
      s16x8 v = *(const s16x8*)(smem + row*72 + cc);
      *(s16x8*)(dst + (size_t)(mbase + row)*DI + colbase + cc) = v;
    }
  }
}

// ---------------- chunked selective scan ----------------
__global__ __launch_bounds__(384) void scan_kernel(
    const unsigned short* __restrict__ xp, const unsigned short* __restrict__ dt,
    const unsigned short* __restrict__ zb, const float* __restrict__ A_log,
    const float* __restrict__ D_vec, unsigned short* __restrict__ yz) {
  int g  = blockIdx.x;
  int di = threadIdx.x;
  size_t base = (size_t)g * 32 * DI + di;
  float a[DS];
  #pragma unroll
  for (int s = 0; s < DS; ++s) a[s] = -__expf(A_log[di*DS + s]);
  float Dv = D_vec[di];
  float h[DS] = {0.f,0.f,0.f,0.f,0.f,0.f,0.f,0.f};
  for (int tt = 0; tt < 32; ++tt) {
    size_t idx = base + (size_t)tt * DI;
    float xv  = bf2f(xp[idx]);
    float dtv = bf2f(dt[idx]);
    float y = 0.f;
    #pragma unroll
    for (int s = 0; s < DS; ++s) {
      h[s] = h[s] * __expf(dtv * a[s]) + xv;
      y += h[s];
    }
    float zv = bf2f(zb[idx]);
    yz[idx] = f2bf(y * zv + xv * Dv);
  }
}

extern "C" void kernel_launch(void* const* d_in, const int* in_sizes, int n_in,
                              void* d_out, int out_size, void* d_ws, size_t ws_size,
                              hipStream_t stream) {
  const float* x     = (const float*)d_in[0];
  const float* gamma = (const float*)d_in[1];
  const float* beta  = (const float*)d_in[2];
  const float* W_in  = (const float*)d_in[3];
  const float* b_in  = (const float*)d_in[4];
  const float* W_dt  = (const float*)d_in[5];
  const float* b_dt  = (const float*)d_in[6];
  const float* A_log = (const float*)d_in[7];
  const float* D_vec = (const float*)d_in[8];
  const float* W_out = (const float*)d_in[9];
  const float* b_out = (const float*)d_in[10];
  float* out = (float*)d_out;

  char* ws = (char*)d_ws;
  size_t off = 0;
  auto alloc = [&](size_t bytes) -> char* {
    char* p = ws + off; off += (bytes + 255) & ~(size_t)255; return p;
  };
  unsigned short* xn    = (unsigned short*)alloc((size_t)M_*DM*2);
  unsigned short* xpb   = (unsigned short*)alloc((size_t)M_*DI*2);
  unsigned short* zb    = (unsigned short*)alloc((size_t)M_*DI*2);
  unsigned short* dtin  = (unsigned short*)alloc((size_t)M_*DI*2);
  unsigned short* dtb   = (unsigned short*)alloc((size_t)M_*DI*2);
  unsigned short* yzb   = dtin;   // dtin dead after GEMM2 -> reuse for yz
  unsigned short* winb  = (unsigned short*)alloc((size_t)3*DI*DM*2);
  unsigned short* wdtb  = (unsigned short*)alloc((size_t)DI*DI*2);
  unsigned short* woutb = (unsigned short*)alloc((size_t)DM*DI*2);

  cvt_kernel<<<dim3((3*DI*DM + 255)/256), 256, 0, stream>>>(W_in, W_dt, W_out, winb, wdtb, woutb);
  ln_kernel<<<dim3(M_/4), 256, 0, stream>>>(x, gamma, beta, xn);
  // GEMM1: xn[M,256] @ W_in[1152,256]^T -> silu(xp), silu(z), dtin
  gemm_ws<1, 8><<<dim3(M_/128, (3*DI)/64), 256, 0, stream>>>(
      xn, winb, b_in, xpb, zb, dtin, nullptr, nullptr, nullptr);
  // GEMM2: dtin[M,384] @ W_dt[384,384]^T ; softplus -> dt
  gemm_ws<2, 12><<<dim3(M_/128, DI/64), 256, 0, stream>>>(
      dtin, wdtb, b_dt, nullptr, nullptr, nullptr, dtb, nullptr, nullptr);
  // scan -> yz = y*z + xp*D
  scan_kernel<<<dim3(M_/32), DI, 0, stream>>>(xpb, dtb, zb, A_log, D_vec, yzb);
  // GEMM3: yz[M,384] @ W_out[256,384]^T + b_out + residual -> out (fp32)
  gemm_ws<3, 12><<<dim3(M_/128, DM/64), 256, 0, stream>>>(
      yzb, woutb, b_out, nullptr, nullptr, nullptr, nullptr, x, out);
}